// Round 4
// baseline (36110.648 us; speedup 1.0000x reference)
//
#include <hip/hip_runtime.h>
#include <math.h>

typedef long long i64;

#define B_    64
#define TIN   128
#define TDEC  128
#define E_    512
#define H_    1024
#define V_    32000
#define H3    3072
#define EH    1536
#define NROWS 8192   // T*B
#define BH    (B_ * H_)

__device__ inline unsigned int ordf(float v) {
  unsigned int u = __float_as_uint(v);
  return (u & 0x80000000u) ? ~u : (u | 0x80000000u);
}

// s-component bi feeds acc[bi][*], w-component c feeds acc[*][c]
__device__ __forceinline__ void fma16(float acc[4][4], float4 s, float4 w) {
  acc[0][0] = fmaf(s.x, w.x, acc[0][0]); acc[0][1] = fmaf(s.x, w.y, acc[0][1]);
  acc[0][2] = fmaf(s.x, w.z, acc[0][2]); acc[0][3] = fmaf(s.x, w.w, acc[0][3]);
  acc[1][0] = fmaf(s.y, w.x, acc[1][0]); acc[1][1] = fmaf(s.y, w.y, acc[1][1]);
  acc[1][2] = fmaf(s.y, w.z, acc[1][2]); acc[1][3] = fmaf(s.y, w.w, acc[1][3]);
  acc[2][0] = fmaf(s.z, w.x, acc[2][0]); acc[2][1] = fmaf(s.z, w.y, acc[2][1]);
  acc[2][2] = fmaf(s.z, w.z, acc[2][2]); acc[2][3] = fmaf(s.z, w.w, acc[2][3]);
  acc[3][0] = fmaf(s.w, w.x, acc[3][0]); acc[3][1] = fmaf(s.w, w.y, acc[3][1]);
  acc[3][2] = fmaf(s.w, w.z, acc[3][2]); acc[3][3] = fmaf(s.w, w.w, acc[3][3]);
}

// ------------------------------------------------------------------
__global__ void diag_fill(float* __restrict__ out, int n, float val) {
  int i = blockIdx.x * blockDim.x + threadIdx.x;
  if (i < n) out[i] = val;
}

__global__ void init_ws(float* __restrict__ hbuf, unsigned long long* __restrict__ amaxkey,
                        float* __restrict__ sumexp) {
  int i = blockIdx.x * blockDim.x + threadIdx.x;
  if (i < 2 * B_ * H_) hbuf[i] = 0.f;
  if (i < NROWS) { amaxkey[i] = 0ull; sumexp[i] = 0.f; }
}

__global__ void prep_tokens(const int* __restrict__ src, const int* __restrict__ tgt,
                            int* __restrict__ tok_src, int* __restrict__ tok_prev) {
  int r = blockIdx.x * blockDim.x + threadIdx.x;
  if (r >= NROWS) return;
  int t = r >> 6, b = r & 63;
  tok_src[r]  = src[b * TIN + t];
  tok_prev[r] = (t == 0) ? 1 : tgt[b * TDEC + (t - 1)];
}

// ------------------------------------------------------------------
// C[r][c] = sum_k emb[tok[r]][k] * W[(n0+c)*wstride + k] + bias[c]  (Ae only now)
__global__ __launch_bounds__(256)
void gemm_gather(const float* __restrict__ emb, const int* __restrict__ tok,
                 const float* __restrict__ W, int wstride,
                 const float* __restrict__ bias,
                 float* __restrict__ C, int ldc) {
  __shared__ float As[32][132];
  __shared__ float Bs[32][136];
  __shared__ int toks[128];
  const int tid = threadIdx.x;
  const int tx = tid & 15, ty = tid >> 4;
  const int r0 = blockIdx.y * 128, n0 = blockIdx.x * 128;
  if (tid < 128) toks[tid] = tok[r0 + tid];
  __syncthreads();
  float acc[8][8];
#pragma unroll
  for (int i = 0; i < 8; ++i)
#pragma unroll
    for (int j = 0; j < 8; ++j) acc[i][j] = 0.f;

  for (int k0 = 0; k0 < E_; k0 += 32) {
#pragma unroll
    for (int j = 0; j < 4; ++j) {
      int s = tid + 256 * j;
      int m = s >> 3, k4 = (s & 7) << 2;
      float4 v = *reinterpret_cast<const float4*>(&emb[(i64)toks[m] * E_ + k0 + k4]);
      As[k4 + 0][m] = v.x; As[k4 + 1][m] = v.y; As[k4 + 2][m] = v.z; As[k4 + 3][m] = v.w;
      float4 u = *reinterpret_cast<const float4*>(&W[(i64)(n0 + m) * wstride + k0 + k4]);
      Bs[k4 + 0][m] = u.x; Bs[k4 + 1][m] = u.y; Bs[k4 + 2][m] = u.z; Bs[k4 + 3][m] = u.w;
    }
    __syncthreads();
#pragma unroll
    for (int k = 0; k < 32; ++k) {
      float a[8], b[8];
      *(float4*)&a[0] = *(float4*)&As[k][ty * 4];
      *(float4*)&a[4] = *(float4*)&As[k][64 + ty * 4];
      *(float4*)&b[0] = *(float4*)&Bs[k][tx * 4];
      *(float4*)&b[4] = *(float4*)&Bs[k][64 + tx * 4];
#pragma unroll
      for (int i = 0; i < 8; ++i)
#pragma unroll
        for (int j = 0; j < 8; ++j)
          acc[i][j] = fmaf(a[i], b[j], acc[i][j]);
    }
    __syncthreads();
  }
#pragma unroll
  for (int i = 0; i < 8; ++i) {
    int rl = (i < 4) ? (ty * 4 + i) : (64 + ty * 4 + i - 4);
    int r = r0 + rl;
#pragma unroll
    for (int j = 0; j < 8; ++j) {
      int cl = (j < 4) ? (tx * 4 + j) : (64 + tx * 4 + j - 4);
      int c = n0 + cl;
      C[(i64)r * ldc + c] = acc[i][j] + bias[c];
    }
  }
}

// ------------------------------------------------------------------
// Encoder step, register-blocked. 256 blocks x 4 h-cols, 512 threads.
// Thread (bg,ac,ks): bg=4 batches, ac in {r,z,gin(E),ghn(H)}, ks=8 k-slices.
// Per k: one b128 S-read + one b128 W-read -> 16 FMA.
__global__ __launch_bounds__(512)
void enc_step2(const float* __restrict__ h_prev, float* __restrict__ h_next,
               const float* __restrict__ emb, const int* __restrict__ tokS,
               const float* __restrict__ Wih, const float* __restrict__ Whh,
               const float* __restrict__ bih, const float* __restrict__ bhh,
               const int* __restrict__ src_len, float* __restrict__ EncRaw, int t) {
  __shared__ float S[64][68];     // [k][b]
  __shared__ float WL[64 * 32];   // [k][quad-swizzled 3 mats x 4 cols]
  __shared__ float red[8 * 1024]; // [ks][ac][c][b]
  __shared__ int toks[64];
  const int tid = threadIdx.x;
  const int n0 = blockIdx.x * 4;
  const int bg = tid & 15, ac = (tid >> 4) & 3, ks = tid >> 6;
  const int b0 = bg * 4;
  if (tid < 64) toks[tid] = tokS[t * B_ + tid];
  float acc[4][4] = {{0}};
  for (int ch = 0; ch < 24; ++ch) {
    const bool isE = ch < 8;
    const int k0 = (isE ? ch : ch - 8) * 64;
    __syncthreads();
    {  // stage S: 64 b x 64 k
      int b = tid & 63, kb = (tid >> 6) * 8;
      const float* src = isE ? &emb[(i64)toks[b] * E_ + k0 + kb]
                             : &h_prev[(i64)b * H_ + k0 + kb];
      float4 v0 = *(const float4*)src;
      float4 v1 = *(const float4*)(src + 4);
      S[kb + 0][b] = v0.x; S[kb + 1][b] = v0.y; S[kb + 2][b] = v0.z; S[kb + 3][b] = v0.w;
      S[kb + 4][b] = v1.x; S[kb + 5][b] = v1.y; S[kb + 6][b] = v1.z; S[kb + 7][b] = v1.w;
    }
    if (tid < 192) {  // stage 3 mats x 4 cols x 64 k, coalesced, quad-XOR swizzle
      int lin = tid * 4;
      int row12 = lin >> 6, k4 = lin & 63;
      int m = row12 >> 2, c = row12 & 3;
      const float* W = isE ? Wih : Whh;
      const int K = isE ? E_ : H_;
      float4 w = *(const float4*)&W[(i64)(m * H_ + n0 + c) * K + k0 + k4];
      int slot = ((m ^ ((k4 >> 2) & 7)) << 2) + c;
      WL[(k4 + 0) * 32 + slot] = w.x;
      WL[(k4 + 1) * 32 + slot] = w.y;
      WL[(k4 + 2) * 32 + slot] = w.z;
      WL[(k4 + 3) * 32 + slot] = w.w;
    }
    __syncthreads();
    const bool active = (ac < 2) || (ac == 2 && isE) || (ac == 3 && !isE);
    if (active) {
      const int m = (ac < 2) ? ac : 2;
#pragma unroll
      for (int kk = ks * 8; kk < ks * 8 + 8; ++kk) {
        float4 sv = *(float4*)&S[kk][b0];
        float4 wv = *(float4*)&WL[kk * 32 + ((m ^ ((kk >> 2) & 7)) << 2)];
        fma16(acc, sv, wv);
      }
    }
  }
  __syncthreads();
#pragma unroll
  for (int bi = 0; bi < 4; ++bi)
#pragma unroll
    for (int c = 0; c < 4; ++c)
      red[ks * 1024 + ac * 256 + c * 64 + b0 + bi] = acc[bi][c];
  __syncthreads();
  if (tid < 256) {
    int b = tid & 63, c = tid >> 6, col = n0 + c;
    float sr = 0, sz = 0, gin = 0, ghn = 0;
#pragma unroll
    for (int k2 = 0; k2 < 8; ++k2) {
      sr  += red[k2 * 1024 +   0 + c * 64 + b];
      sz  += red[k2 * 1024 + 256 + c * 64 + b];
      gin += red[k2 * 1024 + 512 + c * 64 + b];
      ghn += red[k2 * 1024 + 768 + c * 64 + b];
    }
    float r = 1.f / (1.f + expf(-(sr + bih[col] + bhh[col])));
    float z = 1.f / (1.f + expf(-(sz + bih[H_ + col] + bhh[H_ + col])));
    float nn = tanhf(gin + bih[2 * H_ + col] + r * (ghn + bhh[2 * H_ + col]));
    float hpv = h_prev[(i64)b * H_ + col];
    float hnew = (1.f - z) * nn + z * hpv;
    bool valid = t < src_len[b];
    h_next[(i64)b * H_ + col] = valid ? hnew : hpv;
    EncRaw[((i64)b * TIN + t) * H_ + col] = valid ? hnew : 0.f;
  }
}

// ------------------------------------------------------------------
// log_softmax over time axis, in place. layout [B][T][H].
__global__ void ls_time(float* __restrict__ Enc) {
  int idx = blockIdx.x * blockDim.x + threadIdx.x;
  int b = idx >> 10, c = idx & 1023;
  const i64 base = (i64)b * TIN * H_ + c;
  float M = -INFINITY;
  for (int t = 0; t < TIN; ++t) M = fmaxf(M, Enc[base + (i64)t * H_]);
  float S = 0.f;
  for (int t = 0; t < TIN; ++t) S += expf(Enc[base + (i64)t * H_] - M);
  float lg = M + logf(S);
  for (int t = 0; t < TIN; ++t) Enc[base + (i64)t * H_] -= lg;
}

// ------------------------------------------------------------------
// attention scores + softmax + info. 256 blocks (64 b x 4 col-quarters), 512 thr.
__global__ __launch_bounds__(512)
void attn_info2(const float* __restrict__ h_prev, const float* __restrict__ Ae,
                const float* __restrict__ attn_W, const float* __restrict__ EncLS,
                float* __restrict__ info, int t) {
  __shared__ float hl[H_];
  __shared__ float sc[TIN];
  __shared__ float inf2[512];
  const int b = blockIdx.x & 63, quarter = blockIdx.x >> 6;
  const int tid = threadIdx.x;
  if (tid < 256) {
    float4 v = *(const float4*)&h_prev[(i64)b * H_ + tid * 4];
    *(float4*)&hl[tid * 4] = v;
  }
  __syncthreads();
  const int w = tid >> 6, lane = tid & 63;
#pragma unroll
  for (int si = 0; si < 16; ++si) {
    int s = w * 16 + si;
    float p = 0.f;
#pragma unroll
    for (int jj = 0; jj < 16; ++jj) {
      int j = jj * 64 + lane;
      p = fmaf(hl[j], attn_W[(i64)s * EH + E_ + j], p);
    }
#pragma unroll
    for (int off = 32; off > 0; off >>= 1) p += __shfl_down(p, off);
    if (lane == 0) sc[s] = p + Ae[((i64)t * B_ + b) * TIN + s];
  }
  __syncthreads();
  if (tid < 64) {
    float v0 = sc[tid], v1 = sc[tid + 64];
    float mx = fmaxf(v0, v1);
#pragma unroll
    for (int off = 32; off > 0; off >>= 1) mx = fmaxf(mx, __shfl_xor(mx, off));
    float e0 = expf(v0 - mx), e1 = expf(v1 - mx);
    float ss = e0 + e1;
#pragma unroll
    for (int off = 32; off > 0; off >>= 1) ss += __shfl_xor(ss, off);
    sc[tid] = e0 / ss; sc[tid + 64] = e1 / ss;
  }
  __syncthreads();
  {
    int c = quarter * 256 + (tid & 255);
    int th = tid >> 8;
    float acc = 0.f;
    for (int t2 = th * 64; t2 < th * 64 + 64; ++t2)
      acc = fmaf(sc[t2], EncLS[((i64)b * TIN + t2) * H_ + c], acc);
    inf2[tid] = acc;
    __syncthreads();
    if (th == 0) info[(i64)b * H_ + c] = acc + inf2[tid + 256];
  }
}

// ------------------------------------------------------------------
// comb = relu(cat(e, info) @ comb_W.T + b). 256 blocks x 4 cols, 512 thr.
// Thread (bg=4 batches, cs=1 col, ks=8 slices).
__global__ __launch_bounds__(512)
void comb2(const float* __restrict__ info, const float* __restrict__ emb,
           const int* __restrict__ tokP, const float* __restrict__ comb_W,
           const float* __restrict__ comb_b, float* __restrict__ comb, int t) {
  __shared__ float S[64][68];
  __shared__ float WB[64 * 20];
  __shared__ float red[8 * 256];
  __shared__ int toks[64];
  const int tid = threadIdx.x;
  const int n0 = blockIdx.x * 4;
  const int bg = tid & 15, cs = (tid >> 4) & 3, ks = tid >> 6;
  const int b0 = bg * 4;
  if (tid < 64) toks[tid] = tokP[t * B_ + tid];
  float acc[4] = {0, 0, 0, 0};
  for (int ch = 0; ch < 24; ++ch) {
    const bool isE = ch < 8;
    const int k0 = (isE ? ch : ch - 8) * 64;
    __syncthreads();
    {
      int b = tid & 63, kb = (tid >> 6) * 8;
      const float* src = isE ? &emb[(i64)toks[b] * E_ + k0 + kb]
                             : &info[(i64)b * H_ + k0 + kb];
      float4 v0 = *(const float4*)src;
      float4 v1 = *(const float4*)(src + 4);
      S[kb + 0][b] = v0.x; S[kb + 1][b] = v0.y; S[kb + 2][b] = v0.z; S[kb + 3][b] = v0.w;
      S[kb + 4][b] = v1.x; S[kb + 5][b] = v1.y; S[kb + 6][b] = v1.z; S[kb + 7][b] = v1.w;
    }
    if (tid < 64) {
      int k = tid;
      i64 koff = (i64)(isE ? 0 : E_) + k0 + k;
      float4 w;
      w.x = comb_W[(i64)(n0 + 0) * EH + koff];
      w.y = comb_W[(i64)(n0 + 1) * EH + koff];
      w.z = comb_W[(i64)(n0 + 2) * EH + koff];
      w.w = comb_W[(i64)(n0 + 3) * EH + koff];
      *(float4*)&WB[k * 20] = w;
    }
    __syncthreads();
#pragma unroll
    for (int kk = ks * 8; kk < ks * 8 + 8; ++kk) {
      float4 sv = *(float4*)&S[kk][b0];
      float wv = WB[kk * 20 + cs];
      acc[0] = fmaf(sv.x, wv, acc[0]);
      acc[1] = fmaf(sv.y, wv, acc[1]);
      acc[2] = fmaf(sv.z, wv, acc[2]);
      acc[3] = fmaf(sv.w, wv, acc[3]);
    }
  }
  __syncthreads();
#pragma unroll
  for (int bi = 0; bi < 4; ++bi)
    red[ks * 256 + cs * 64 + b0 + bi] = acc[bi];
  __syncthreads();
  if (tid < 256) {
    int b = tid & 63, c = tid >> 6;
    float s = comb_b[n0 + c];
#pragma unroll
    for (int k2 = 0; k2 < 8; ++k2) s += red[k2 * 256 + c * 64 + b];
    comb[(i64)b * H_ + n0 + c] = fmaxf(s, 0.f);
  }
}

// ------------------------------------------------------------------
// decoder GRU step. 256 blocks x 4 h-cols, 512 thr; (bg,ac,ks) mapping.
// ac 0/1: r/z over (h@Whh + comb@Wih); ac 2: gin (comb@Win); ac 3: ghn (h@Whn).
__global__ __launch_bounds__(512)
void dec_gru2(const float* __restrict__ h_prev, const float* __restrict__ comb,
              const float* __restrict__ Wih, const float* __restrict__ Whh,
              const float* __restrict__ bih, const float* __restrict__ bhh,
              float* __restrict__ h_out) {
  __shared__ float S1[64][68];    // h chunk
  __shared__ float S2[64][68];    // comb chunk
  __shared__ float WL[64 * 32];   // 6 mats x 4 cols, quad-swizzled
  __shared__ float red[8 * 1024];
  const int tid = threadIdx.x;
  const int n0 = blockIdx.x * 4;
  const int bg = tid & 15, ac = (tid >> 4) & 3, ks = tid >> 6;
  const int b0 = bg * 4;
  float acc[4][4] = {{0}};
  for (int ch = 0; ch < 16; ++ch) {
    const int k0 = ch * 64;
    __syncthreads();
    {
      int b = tid & 63, kb = (tid >> 6) * 8;
      const float* s1 = &h_prev[(i64)b * H_ + k0 + kb];
      const float* s2 = &comb[(i64)b * H_ + k0 + kb];
      float4 v0 = *(const float4*)s1, v1 = *(const float4*)(s1 + 4);
      S1[kb + 0][b] = v0.x; S1[kb + 1][b] = v0.y; S1[kb + 2][b] = v0.z; S1[kb + 3][b] = v0.w;
      S1[kb + 4][b] = v1.x; S1[kb + 5][b] = v1.y; S1[kb + 6][b] = v1.z; S1[kb + 7][b] = v1.w;
      float4 u0 = *(const float4*)s2, u1 = *(const float4*)(s2 + 4);
      S2[kb + 0][b] = u0.x; S2[kb + 1][b] = u0.y; S2[kb + 2][b] = u0.z; S2[kb + 3][b] = u0.w;
      S2[kb + 4][b] = u1.x; S2[kb + 5][b] = u1.y; S2[kb + 6][b] = u1.z; S2[kb + 7][b] = u1.w;
    }
    if (tid < 384) {  // 6 mats: m = 0 Whh_r,1 Wih_r,2 Whh_z,3 Wih_z,4 Whh_n,5 Wih_n
      int lin = tid * 4;
      int row24 = lin >> 6, k4 = lin & 63;
      int m = row24 >> 2, c = row24 & 3;
      int g = m >> 1;
      const float* W = (m & 1) ? Wih : Whh;
      float4 w = *(const float4*)&W[(i64)(g * H_ + n0 + c) * H_ + k0 + k4];
      int slot = ((m ^ ((k4 >> 2) & 7)) << 2) + c;
      WL[(k4 + 0) * 32 + slot] = w.x;
      WL[(k4 + 1) * 32 + slot] = w.y;
      WL[(k4 + 2) * 32 + slot] = w.z;
      WL[(k4 + 3) * 32 + slot] = w.w;
    }
    __syncthreads();
    if (ac < 2) {
#pragma unroll
      for (int kk = ks * 8; kk < ks * 8 + 8; ++kk) {
        int key = (kk >> 2) & 7;
        float4 h4 = *(float4*)&S1[kk][b0];
        float4 c4 = *(float4*)&S2[kk][b0];
        float4 wh = *(float4*)&WL[kk * 32 + (((2 * ac) ^ key) << 2)];
        float4 wi = *(float4*)&WL[kk * 32 + (((2 * ac + 1) ^ key) << 2)];
        fma16(acc, h4, wh);
        fma16(acc, c4, wi);
      }
    } else if (ac == 2) {  // gin: comb @ Wih_n (m=5)
#pragma unroll
      for (int kk = ks * 8; kk < ks * 8 + 8; ++kk) {
        int key = (kk >> 2) & 7;
        float4 c4 = *(float4*)&S2[kk][b0];
        float4 wi = *(float4*)&WL[kk * 32 + ((5 ^ key) << 2)];
        fma16(acc, c4, wi);
      }
    } else {               // ghn: h @ Whh_n (m=4)
#pragma unroll
      for (int kk = ks * 8; kk < ks * 8 + 8; ++kk) {
        int key = (kk >> 2) & 7;
        float4 h4 = *(float4*)&S1[kk][b0];
        float4 wh = *(float4*)&WL[kk * 32 + ((4 ^ key) << 2)];
        fma16(acc, h4, wh);
      }
    }
  }
  __syncthreads();
#pragma unroll
  for (int bi = 0; bi < 4; ++bi)
#pragma unroll
    for (int c = 0; c < 4; ++c)
      red[ks * 1024 + ac * 256 + c * 64 + b0 + bi] = acc[bi][c];
  __syncthreads();
  if (tid < 256) {
    int b = tid & 63, c = tid >> 6, col = n0 + c;
    float sr = 0, sz = 0, gin = 0, ghn = 0;
#pragma unroll
    for (int k2 = 0; k2 < 8; ++k2) {
      sr  += red[k2 * 1024 +   0 + c * 64 + b];
      sz  += red[k2 * 1024 + 256 + c * 64 + b];
      gin += red[k2 * 1024 + 512 + c * 64 + b];
      ghn += red[k2 * 1024 + 768 + c * 64 + b];
    }
    float r = 1.f / (1.f + expf(-(sr + bih[col] + bhh[col])));
    float z = 1.f / (1.f + expf(-(sz + bih[H_ + col] + bhh[H_ + col])));
    float nn = tanhf(gin + bih[2 * H_ + col] + r * (ghn + bhh[2 * H_ + col]));
    float hpv = h_prev[(i64)b * H_ + col];
    h_out[(i64)b * H_ + col] = (1.f - z) * nn + z * hpv;
  }
}

// ------------------------------------------------------------------
// batched logits GEMM, fused per-row atomic argmax + atomic sum(exp(v)).
// grid (250, 64): 128x128 tile of C[8192][32000]. LDS union -> 34 KB -> 4 blk/CU.
__global__ __launch_bounds__(256)
void logits_fused(const float* __restrict__ A, const float* __restrict__ Wout,
                  const float* __restrict__ outb, const int* __restrict__ tlen,
                  unsigned long long* __restrict__ amaxkey, float* __restrict__ sumexp) {
  __shared__ union {
    struct { float As[32][132]; float Bs[32][136]; } g;
    struct { float redm[128][17]; int redi[128][17]; float reds[128][17]; } r;
  } sh;
  const int tid = threadIdx.x;
  const int tx = tid & 15, ty = tid >> 4;
  const int r0 = blockIdx.y * 128, n0 = blockIdx.x * 128;
  float acc[8][8];
#pragma unroll
  for (int i = 0; i < 8; ++i)
#pragma unroll
    for (int j = 0; j < 8; ++j) acc[i][j] = 0.f;

  for (int k0 = 0; k0 < H_; k0 += 32) {
#pragma unroll
    for (int j = 0; j < 4; ++j) {
      int s = tid + 256 * j;
      int m = s >> 3, k4 = (s & 7) << 2;
      float4 v = *reinterpret_cast<const float4*>(&A[(i64)(r0 + m) * H_ + k0 + k4]);
      sh.g.As[k4 + 0][m] = v.x; sh.g.As[k4 + 1][m] = v.y;
      sh.g.As[k4 + 2][m] = v.z; sh.g.As[k4 + 3][m] = v.w;
      float4 u = *reinterpret_cast<const float4*>(&Wout[(i64)(n0 + m) * H_ + k0 + k4]);
      sh.g.Bs[k4 + 0][m] = u.x; sh.g.Bs[k4 + 1][m] = u.y;
      sh.g.Bs[k4 + 2][m] = u.z; sh.g.Bs[k4 + 3][m] = u.w;
    }
    __syncthreads();
#pragma unroll
    for (int k = 0; k < 32; ++k) {
      float a[8], b[8];
      *(float4*)&a[0] = *(float4*)&sh.g.As[k][ty * 4];
      *(float4*)&a[4] = *(float4*)&sh.g.As[k][64 + ty * 4];
      *(float4*)&b[0] = *(float4*)&sh.g.Bs[k][tx * 4];
      *(float4*)&b[4] = *(float4*)&sh.g.Bs[k][64 + tx * 4];
#pragma unroll
      for (int i = 0; i < 8; ++i)
#pragma unroll
        for (int j = 0; j < 8; ++j)
          acc[i][j] = fmaf(a[i], b[j], acc[i][j]);
    }
    __syncthreads();
  }

  int cols[8], rloc[8];
#pragma unroll
  for (int j = 0; j < 8; ++j) cols[j] = n0 + ((j < 4) ? (tx * 4 + j) : (64 + tx * 4 + j - 4));
#pragma unroll
  for (int i = 0; i < 8; ++i) rloc[i] = (i < 4) ? (ty * 4 + i) : (64 + ty * 4 + i - 4);

#pragma unroll
  for (int i = 0; i < 8; ++i) {
    int r = r0 + rloc[i];
    int t = r >> 6, b = r & 63;
    bool m = t < tlen[b];
    float lm = -INFINITY; int li = 0x7fffffff; float ls = 0.f;
#pragma unroll
    for (int j = 0; j < 8; ++j) {
      float v = acc[i][j] + outb[cols[j]];
      if (m && cols[j] >= 2 && cols[j] <= 4) v = 0.f;   // wipeEOS
      ls += expf(v);
      if (v > lm || (v == lm && cols[j] < li)) { lm = v; li = cols[j]; }
    }
    sh.r.redm[rloc[i]][tx] = lm; sh.r.redi[rloc[i]][tx] = li; sh.r.reds[rloc[i]][tx] = ls;
  }
  __syncthreads();
  if (tid < 128) {
    float M = -INFINITY; int I = 0x7fffffff; float S = 0.f;
#pragma unroll
    for (int x = 0; x < 16; ++x) {
      float v = sh.r.redm[tid][x]; int id = sh.r.redi[tid][x];
      if (v > M || (v == M && id < I)) { M = v; I = id; }
      S += sh.r.reds[tid][x];
    }
    unsigned long long key = ((unsigned long long)ordf(M) << 32) | (0xFFFFFFFFu - (unsigned)I);
    atomicMax(&amaxkey[r0 + tid], key);
    atomicAdd(&sumexp[r0 + tid], S);
  }
}

// ------------------------------------------------------------------
__global__ void tlogit_kernel(const float* __restrict__ Hd, const float* __restrict__ Wout,
                              const float* __restrict__ outb, const int* __restrict__ tgt,
                              const int* __restrict__ tlen, float* __restrict__ tlog) {
  const int tid = threadIdx.x;
  const int w = tid >> 6, lane = tid & 63;
  const int r = blockIdx.x * 4 + w;
  const int t = r >> 6, b = r & 63;
  const int tg = tgt[b * TDEC + t];
  float p = 0.f;
#pragma unroll
  for (int jj = 0; jj < 16; ++jj) {
    int j = jj * 64 + lane;
    p = fmaf(Hd[(i64)r * H_ + j], Wout[(i64)tg * H_ + j], p);
  }
#pragma unroll
  for (int off = 32; off > 0; off >>= 1) p += __shfl_down(p, off);
  if (lane == 0) {
    float v = p + outb[tg];
    if ((t < tlen[b]) && tg >= 2 && tg <= 4) v = 0.f;
    tlog[r] = v;
  }
}

__global__ void merge_kernel(const unsigned long long* __restrict__ amaxkey,
                             const float* __restrict__ sumexp,
                             const float* __restrict__ tlog,
                             const int* __restrict__ tlen,
                             float* __restrict__ out, float* __restrict__ loss_t) {
  const int t = blockIdx.x, b = threadIdx.x;
  const int r = t * 64 + b;
  unsigned long long key = amaxkey[r];
  int I = (int)(0xFFFFFFFFu - (unsigned)(key & 0xFFFFFFFFull));
  float lse = logf(sumexp[r]);
  float ce = lse - tlog[r];
  bool m = t < tlen[b];
  out[b * TDEC + t] = (float)I;
  float num = m ? ce : 0.f;
  float den = m ? 1.f : 0.f;
#pragma unroll
  for (int off = 32; off > 0; off >>= 1) {
    num += __shfl_down(num, off);
    den += __shfl_down(den, off);
  }
  if (b == 0) loss_t[t] = num / den;
}

__global__ void loss_sum(const float* __restrict__ loss_t, float* __restrict__ out) {
  const int tid = threadIdx.x;
  float v = loss_t[tid];
#pragma unroll
  for (int off = 32; off > 0; off >>= 1) v += __shfl_down(v, off);
  __shared__ float ps[2];
  if ((tid & 63) == 0) ps[tid >> 6] = v;
  __syncthreads();
  if (tid == 0) out[B_ * TDEC] = ps[0] + ps[1];
}

// ------------------------------------------------------------------
extern "C" void kernel_launch(void* const* d_in, const int* in_sizes, int n_in,
                              void* d_out, int out_size, void* d_ws, size_t ws_size,
                              hipStream_t stream) {
  const float* emb     = (const float*)d_in[0];
  const float* enc_Wih = (const float*)d_in[1];
  const float* enc_Whh = (const float*)d_in[2];
  const float* enc_bih = (const float*)d_in[3];
  const float* enc_bhh = (const float*)d_in[4];
  const float* attn_W  = (const float*)d_in[5];
  const float* attn_b  = (const float*)d_in[6];
  const float* comb_W  = (const float*)d_in[7];
  const float* comb_b  = (const float*)d_in[8];
  const float* dec_Wih = (const float*)d_in[9];
  const float* dec_Whh = (const float*)d_in[10];
  const float* dec_bih = (const float*)d_in[11];
  const float* dec_bhh = (const float*)d_in[12];
  const float* out_W   = (const float*)d_in[13];
  const float* out_b   = (const float*)d_in[14];
  const int* src_tok = (const int*)d_in[15];
  const int* tgt_tok;
  const int* src_len;
  const int* tgt_len;
  if (in_sizes[16] == B_ * TDEC) {
    tgt_tok = (const int*)d_in[16];
    src_len = (const int*)d_in[17];
    tgt_len = (const int*)d_in[18];
  } else {
    src_len = (const int*)d_in[16];
    tgt_len = (const int*)d_in[17];
    tgt_tok = (const int*)d_in[18];
  }
  float* out = (float*)d_out;
  char* wsb = (char*)d_ws;
  size_t off = 0;
  auto alloc = [&](size_t bytes) { void* p = wsb + off; off += (bytes + 255) & ~(size_t)255; return p; };

  float* EncLS = (float*)alloc((size_t)NROWS * H_ * 4);       // [B][T][H]
  float* hbuf  = (float*)alloc(2ull * B_ * H_ * 4);
  float* Ae    = (float*)alloc((size_t)NROWS * TIN * 4);
  float* Hdec  = (float*)alloc((size_t)NROWS * H_ * 4);       // [T][B][H]
  float* info  = (float*)alloc((size_t)B_ * H_ * 4);
  float* comb  = (float*)alloc((size_t)B_ * H_ * 4);
  unsigned long long* amaxkey = (unsigned long long*)alloc((size_t)NROWS * 8);
  float* sumexp = (float*)alloc((size_t)NROWS * 4);
  float* tlog  = (float*)alloc((size_t)NROWS * 4);
  float* lossT = (float*)alloc(TDEC * 4);
  int* tokS    = (int*)alloc(NROWS * 4);
  int* tokP    = (int*)alloc(NROWS * 4);

  if (off > ws_size) {
    diag_fill<<<(out_size + 255) / 256, 256, 0, stream>>>(out, out_size, (float)ws_size);
    return;
  }

  init_ws<<<512, 256, 0, stream>>>(hbuf, amaxkey, sumexp);
  prep_tokens<<<32, 256, 0, stream>>>(src_tok, tgt_tok, tokS, tokP);
  gemm_gather<<<dim3(1, 64), 256, 0, stream>>>(emb, tokP, attn_W, EH, attn_b, Ae, TIN);

  for (int t = 0; t < TIN; ++t) {
    const float* hp = hbuf + (size_t)(t & 1) * BH;
    float* hn = hbuf + (size_t)((t + 1) & 1) * BH;
    enc_step2<<<256, 512, 0, stream>>>(hp, hn, emb, tokS, enc_Wih, enc_Whh,
                                       enc_bih, enc_bhh, src_len, EncLS, t);
  }
  ls_time<<<256, 256, 0, stream>>>(EncLS);

  for (int t = 0; t < TDEC; ++t) {
    const float* hp = (t == 0) ? hbuf : (Hdec + (i64)(t - 1) * BH);
    attn_info2<<<256, 512, 0, stream>>>(hp, Ae, attn_W, EncLS, info, t);
    comb2<<<256, 512, 0, stream>>>(info, emb, tokP, comb_W, comb_b, comb, t);
    dec_gru2<<<256, 512, 0, stream>>>(hp, comb, dec_Wih, dec_Whh, dec_bih, dec_bhh,
                                      Hdec + (i64)t * BH);
  }

  logits_fused<<<dim3(250, 64), 256, 0, stream>>>(Hdec, out_W, out_b, tgt_len, amaxkey, sumexp);
  tlogit_kernel<<<2048, 256, 0, stream>>>(Hdec, out_W, out_b, tgt_tok, tgt_len, tlog);
  merge_kernel<<<128, 64, 0, stream>>>(amaxkey, sumexp, tlog, tgt_len, out, lossT);
  loss_sum<<<1, 128, 0, stream>>>(lossT, out);
}